// Round 3
// baseline (967.616 us; speedup 1.0000x reference)
//
#include <hip/hip_runtime.h>
#include <hip/hip_bf16.h>
#include <stdint.h>
#include <stddef.h>

using bf16 = __hip_bfloat16;
typedef short s16x8 __attribute__((ext_vector_type(8)));   // 8 bf16 = one MFMA frag (4 VGPRs)
typedef float f32x4 __attribute__((ext_vector_type(4)));

#define MFMA16(a, b, c) __builtin_amdgcn_mfma_f32_16x16x32_bf16((a), (b), (c), 0, 0, 0)

typedef __attribute__((address_space(1))) void gvoid;
typedef __attribute__((address_space(3))) void lvoid;
// global -> LDS direct copy, 16B per lane; LDS dest = wave-uniform base + lane*16
#define GLL16(gp, lp) __builtin_amdgcn_global_load_lds((gvoid*)(void*)(gp), (lvoid*)(lp), 16, 0, 0)

__device__ __forceinline__ short f2bf(float x) {
    bf16 h = __float2bfloat16(x);
    return __builtin_bit_cast(short, h);
}

// f32 -> bf16 elementwise, n % 1024 == 0, grid*block*4 == n
__global__ void cvt_bf16(const float* __restrict__ in, bf16* __restrict__ out, int n) {
    int i = (blockIdx.x * blockDim.x + threadIdx.x) * 4;
    if (i < n) {
        float4 v = *(const float4*)(in + i);
        out[i + 0] = __float2bfloat16(v.x);
        out[i + 1] = __float2bfloat16(v.y);
        out[i + 2] = __float2bfloat16(v.z);
        out[i + 3] = __float2bfloat16(v.w);
    }
}

// zero n bf16 (n % 2048 == 0), grid*block*8 == n
__global__ void zero_bf16(bf16* __restrict__ p, int n) {
    int i = (blockIdx.x * blockDim.x + threadIdx.x) * 8;
    if (i < n) {
        s16x8 z = {0, 0, 0, 0, 0, 0, 0, 0};
        *(s16x8*)(p + i) = z;
    }
}

// 1024x1024 bf16 transpose: out = in^T.  grid (16,16), block 256.
__global__ __launch_bounds__(256) void transpose_bf16(
    const bf16* __restrict__ in, bf16* __restrict__ out)
{
    __shared__ bf16 t[64][72];
    const int bx = blockIdx.x * 64, by = blockIdx.y * 64;
    const int tid = threadIdx.x;
#pragma unroll
    for (int i = 0; i < 2; ++i) {
        const int r = (tid >> 3) + i * 32, c = (tid & 7) * 8;
        *(s16x8*)&t[r][c] = *(const s16x8*)(in + (size_t)(bx + r) * 1024 + by + c);
    }
    __syncthreads();
#pragma unroll
    for (int i = 0; i < 2; ++i) {
        const int r = (tid >> 3) + i * 32, c = (tid & 7) * 8;
        s16x8 v;
#pragma unroll
        for (int k = 0; k < 8; ++k) v[k] = __builtin_bit_cast(short, t[c + k][r]);
        *(s16x8*)(out + (size_t)(by + r) * 1024 + bx + c) = v;
    }
}

// ---------------------------------------------------------------------------
// C[om(m)][n] = bias[n] + sum_k A[m][k] * Bt[n][k]     (K = N = 1024)
// Double-buffered LDS + issue-early prefetch (T3-minimum 2-phase): loads for
// K-step t+1 are issued BEFORE computing step t; single __syncthreads per step
// (its vmcnt/lgkm drain is cheap -- loads had the whole MFMA phase in flight).
// A_F32: A loaded global->reg early (T14 split), converted + ds_written after
// the MFMAs.  XCD-aware swizzle (T1) unchanged from round 2.
// ---------------------------------------------------------------------------
template<bool A_F32, bool OUT_F32, int REMAP>
__global__ __launch_bounds__(256) void gemm_bt(
    const void* __restrict__ Ap, const bf16* __restrict__ Bt,
    const float* __restrict__ bias, void* __restrict__ Cp)
{
    __shared__ __align__(16) bf16 lA[2][128 * 64];
    __shared__ __align__(16) bf16 lB[2][128 * 64];

    const int tid  = threadIdx.x;
    const int lane = tid & 63, wv = tid >> 6;
    const int wm = wv & 1, wn = wv >> 1;
    const int quad = lane >> 4, l16 = lane & 15;

    // XCD-aware swizzle: lid -> wid (XCD-contiguous), n-tile fastest per m-slab.
    const int lid = blockIdx.y * 256 + blockIdx.x;      // grid (256,8), x fastest
    const int wid = (lid & 7) * 256 + (lid >> 3);       // 2048/8 = 256 per XCD
    const int m0 = (wid >> 3) * 128;
    const int n0 = (wid & 7) * 128;

    const int sr = lane >> 3;
    const int sc = ((lane & 7) ^ sr) * 8;   // element offset of swizzled 16B chunk
    const int ar = tid >> 1;
    const int ah = tid & 1;

    const float* Af = (const float*)Ap;
    const bf16*  Ab = (const bf16*)Ap;

    f32x4 acc[4][4] = {};
    float4 vr[4][2];          // f32-A register staging (A_F32 only)

#define STAGE_B(buf, ko) do { \
    _Pragma("unroll") \
    for (int qi = 0; qi < 4; ++qi) { \
        const int q = wv * 4 + qi; \
        GLL16(Bt + (size_t)(n0 + q * 8 + sr) * 1024 + (ko) + sc, (char*)lB[buf] + q * 1024); \
    } } while (0)
#define STAGE_A_BF(buf, ko) do { \
    _Pragma("unroll") \
    for (int qi = 0; qi < 4; ++qi) { \
        const int q = wv * 4 + qi; \
        GLL16(Ab + (size_t)(m0 + q * 8 + sr) * 1024 + (ko) + sc, (char*)lA[buf] + q * 1024); \
    } } while (0)
#define LOAD_A_F32(ko) do { \
    _Pragma("unroll") \
    for (int i = 0; i < 4; ++i) { \
        const int c = ah * 4 + i; \
        const float* srcp = Af + (size_t)(m0 + ar) * 1024 + (ko) + c * 8; \
        vr[i][0] = *(const float4*)(srcp); \
        vr[i][1] = *(const float4*)(srcp + 4); \
    } } while (0)
#define WRITE_A_F32(buf) do { \
    _Pragma("unroll") \
    for (int i = 0; i < 4; ++i) { \
        const int c = ah * 4 + i; \
        s16x8 w; \
        w[0] = f2bf(vr[i][0].x); w[1] = f2bf(vr[i][0].y); w[2] = f2bf(vr[i][0].z); w[3] = f2bf(vr[i][0].w); \
        w[4] = f2bf(vr[i][1].x); w[5] = f2bf(vr[i][1].y); w[6] = f2bf(vr[i][1].z); w[7] = f2bf(vr[i][1].w); \
        *(s16x8*)((char*)lA[buf] + ar * 128 + ((c ^ (ar & 7)) << 4)) = w; \
    } } while (0)

    // prologue: stage ko=0 into buffer 0
    if constexpr (A_F32) { LOAD_A_F32(0); WRITE_A_F32(0); }
    else                 { STAGE_A_BF(0, 0); }
    STAGE_B(0, 0);
    __syncthreads();

    int cur = 0;
    for (int t = 0; t < 16; ++t) {
        const int nxt = cur ^ 1;
        if (t < 15) {
            const int ko = (t + 1) * 64;
            if constexpr (A_F32) LOAD_A_F32(ko);
            else                 STAGE_A_BF(nxt, ko);
            STAGE_B(nxt, ko);
        }
#pragma unroll
        for (int kc = 0; kc < 2; ++kc) {
            s16x8 af[4], bg[4];
#pragma unroll
            for (int mt = 0; mt < 4; ++mt) {
                const int r = 64 * wm + 16 * mt + l16;
                const int c = kc * 4 + quad;
                af[mt] = *(const s16x8*)((const char*)lA[cur] + r * 128 + ((c ^ (r & 7)) * 16));
            }
#pragma unroll
            for (int nt = 0; nt < 4; ++nt) {
                const int r = 64 * wn + 16 * nt + l16;
                const int c = kc * 4 + quad;
                bg[nt] = *(const s16x8*)((const char*)lB[cur] + r * 128 + ((c ^ (r & 7)) * 16));
            }
#pragma unroll
            for (int mt = 0; mt < 4; ++mt)
#pragma unroll
                for (int nt = 0; nt < 4; ++nt)
                    acc[mt][nt] = MFMA16(af[mt], bg[nt], acc[mt][nt]);
        }
        if constexpr (A_F32) { if (t < 15) WRITE_A_F32(nxt); }
        __syncthreads();
        cur = nxt;
    }
#undef STAGE_B
#undef STAGE_A_BF
#undef LOAD_A_F32
#undef WRITE_A_F32

    float bv[4];
#pragma unroll
    for (int nt = 0; nt < 4; ++nt)
        bv[nt] = bias[n0 + 64 * wn + 16 * nt + l16];

    // D layout: row = quad*4 + reg, col = lane&15  (m89/m91-verified)
#pragma unroll
    for (int mt = 0; mt < 4; ++mt) {
#pragma unroll
        for (int r = 0; r < 4; ++r) {
            const int m = m0 + 64 * wm + 16 * mt + 4 * quad + r;
            int om = m;
            if constexpr (REMAP == 1)      om = ((m & 511) << 6) | (m >> 9); // b*512+t -> t*64+b
            else if constexpr (REMAP == 2) om = ((m & 63) << 9) | (m >> 6);  // t*64+b -> b*512+t
#pragma unroll
            for (int nt = 0; nt < 4; ++nt) {
                const int n = n0 + 64 * wn + 16 * nt + l16;
                const float val = acc[mt][nt][r] + bv[nt];
                if constexpr (OUT_F32) ((float*)Cp)[(size_t)om * 1024 + n] = val;
                else ((bf16*)Cp)[(size_t)om * 1024 + n] = __float2bfloat16(val);
            }
        }
    }
}

// ---------------------------------------------------------------------------
// Power chain: D[z] = A[z] @ Bt^T.  Same dbuf-prefetch structure. grid (8,8,z).
// ---------------------------------------------------------------------------
__global__ __launch_bounds__(256) void powmul(
    const bf16* __restrict__ Abase, const bf16* __restrict__ Bt,
    bf16* __restrict__ Dbase)
{
    __shared__ __align__(16) bf16 lA[2][128 * 64];
    __shared__ __align__(16) bf16 lB[2][128 * 64];
    const int tid  = threadIdx.x;
    const int lane = tid & 63, wv = tid >> 6;
    const int wm = wv & 1, wn = wv >> 1;
    const int quad = lane >> 4, l16 = lane & 15;
    const int m0 = blockIdx.x * 128, n0 = blockIdx.y * 128;
    const bf16* A = Abase + (size_t)blockIdx.z * 1048576;
    bf16* D       = Dbase + (size_t)blockIdx.z * 1048576;
    const int sr = lane >> 3;
    const int sc = ((lane & 7) ^ sr) * 8;

#define STAGE_AB(buf, ko) do { \
    _Pragma("unroll") \
    for (int qi = 0; qi < 4; ++qi) { \
        const int q = wv * 4 + qi; \
        GLL16(A  + (size_t)(m0 + q * 8 + sr) * 1024 + (ko) + sc, (char*)lA[buf] + q * 1024); \
        GLL16(Bt + (size_t)(n0 + q * 8 + sr) * 1024 + (ko) + sc, (char*)lB[buf] + q * 1024); \
    } } while (0)

    f32x4 acc[4][4] = {};
    STAGE_AB(0, 0);
    __syncthreads();
    int cur = 0;
    for (int t = 0; t < 16; ++t) {
        const int nxt = cur ^ 1;
        if (t < 15) STAGE_AB(nxt, (t + 1) * 64);
#pragma unroll
        for (int kc = 0; kc < 2; ++kc) {
            s16x8 af[4], bg[4];
#pragma unroll
            for (int mt = 0; mt < 4; ++mt) {
                const int r = 64 * wm + 16 * mt + l16;
                const int c = kc * 4 + quad;
                af[mt] = *(const s16x8*)((const char*)lA[cur] + r * 128 + ((c ^ (r & 7)) * 16));
            }
#pragma unroll
            for (int nt = 0; nt < 4; ++nt) {
                const int r = 64 * wn + 16 * nt + l16;
                const int c = kc * 4 + quad;
                bg[nt] = *(const s16x8*)((const char*)lB[cur] + r * 128 + ((c ^ (r & 7)) * 16));
            }
#pragma unroll
            for (int mt = 0; mt < 4; ++mt)
#pragma unroll
                for (int nt = 0; nt < 4; ++nt)
                    acc[mt][nt] = MFMA16(af[mt], bg[nt], acc[mt][nt]);
        }
        __syncthreads();
        cur = nxt;
    }
#undef STAGE_AB
#pragma unroll
    for (int mt = 0; mt < 4; ++mt)
#pragma unroll
        for (int r = 0; r < 4; ++r) {
            const int m = m0 + 64 * wm + 16 * mt + 4 * quad + r;
#pragma unroll
            for (int nt = 0; nt < 4; ++nt) {
                const int n = n0 + 64 * wn + 16 * nt + l16;
                D[(size_t)m * 1024 + n] = __float2bfloat16(acc[mt][nt][r]);
            }
        }
}

// ---------------------------------------------------------------------------
// Local scan step j: rows t = c*16+j:  UA[t] += UA[t-1] @ Waa^T
// dbuf-prefetch structure; 64x128 tile, 4 waves 64x32.  grid (32, 8).
// ---------------------------------------------------------------------------
__global__ __launch_bounds__(256) void local_step(
    const bf16* __restrict__ Bt, bf16* __restrict__ UA, int j)
{
    __shared__ __align__(16) bf16 lA[2][64 * 64];
    __shared__ __align__(16) bf16 lB[2][128 * 64];
    const int tid = threadIdx.x;
    const int lane = tid & 63, wv = tid >> 6;
    const int quad = lane >> 4, l16 = lane & 15;
    const int n0 = blockIdx.y * 128;
    const int t_ = blockIdx.x * 16 + j;
    const bf16* src = UA + (size_t)(t_ - 1) * 64 * 1024;
    bf16* dst       = UA + (size_t)t_ * 64 * 1024;
    const int sr = lane >> 3;
    const int sc = ((lane & 7) ^ sr) * 8;

#define STAGE_AB(buf, ko) do { \
    _Pragma("unroll") \
    for (int qi = 0; qi < 2; ++qi) { \
        const int q = wv * 2 + qi; \
        GLL16(src + (size_t)(q * 8 + sr) * 1024 + (ko) + sc, (char*)lA[buf] + q * 1024); \
    } \
    _Pragma("unroll") \
    for (int qi = 0; qi < 4; ++qi) { \
        const int q = wv * 4 + qi; \
        GLL16(Bt + (size_t)(n0 + q * 8 + sr) * 1024 + (ko) + sc, (char*)lB[buf] + q * 1024); \
    } } while (0)

    f32x4 acc[4][2] = {};
    STAGE_AB(0, 0);
    __syncthreads();
    int cur = 0;
    for (int t = 0; t < 16; ++t) {
        const int nxt = cur ^ 1;
        if (t < 15) STAGE_AB(nxt, (t + 1) * 64);
#pragma unroll
        for (int kc = 0; kc < 2; ++kc) {
            s16x8 af[4], bg[2];
#pragma unroll
            for (int mt = 0; mt < 4; ++mt) {
                const int r = 16 * mt + l16;
                const int c = kc * 4 + quad;
                af[mt] = *(const s16x8*)((const char*)lA[cur] + r * 128 + ((c ^ (r & 7)) * 16));
            }
#pragma unroll
            for (int nt = 0; nt < 2; ++nt) {
                const int r = 32 * wv + 16 * nt + l16;
                const int c = kc * 4 + quad;
                bg[nt] = *(const s16x8*)((const char*)lB[cur] + r * 128 + ((c ^ (r & 7)) * 16));
            }
#pragma unroll
            for (int mt = 0; mt < 4; ++mt)
#pragma unroll
                for (int nt = 0; nt < 2; ++nt)
                    acc[mt][nt] = MFMA16(af[mt], bg[nt], acc[mt][nt]);
        }
        __syncthreads();
        cur = nxt;
    }
#undef STAGE_AB
#pragma unroll
    for (int mt = 0; mt < 4; ++mt)
#pragma unroll
        for (int r = 0; r < 4; ++r) {
            const int b = 16 * mt + 4 * quad + r;
#pragma unroll
            for (int nt = 0; nt < 2; ++nt) {
                const int n = n0 + 32 * wv + 16 * nt + l16;
                bf16* p = dst + (size_t)b * 1024 + n;
                *p = __float2bfloat16(acc[mt][nt][r] + __bfloat162float(*p));
            }
        }
}

// ---------------------------------------------------------------------------
// Carry step: dst[b][n] = lend[b][n] + sum_k src[b][k] * P16[n][k]
// Launch-latency floor; unchanged.  256 blocks x 1 wave.
// ---------------------------------------------------------------------------
__global__ __launch_bounds__(64, 1) void carry_step(
    const bf16* __restrict__ P16, const bf16* __restrict__ lend,
    const bf16* __restrict__ src, bf16* __restrict__ dst)
{
    const int lane = threadIdx.x;
    const int quad = lane >> 4, l16 = lane & 15;
    const int bi = blockIdx.x & 3, nj = blockIdx.x >> 2;

    const bf16* arow = src + ((size_t)(16 * bi + l16)) * 1024;
    const bf16* wrow = P16 + ((size_t)(16 * nj + l16)) * 1024;

    const bf16* urow = lend + ((size_t)(16 * bi + 4 * quad)) * 1024 + 16 * nj + l16;
    f32x4 acc;
#pragma unroll
    for (int rr = 0; rr < 4; ++rr)
        acc[rr] = __bfloat162float(urow[(size_t)rr * 1024]);

    s16x8 av[32], wf[32];
#pragma unroll
    for (int kc = 0; kc < 32; ++kc) {
        av[kc] = *(const s16x8*)(arow + kc * 32 + quad * 8);
        wf[kc] = *(const s16x8*)(wrow + kc * 32 + quad * 8);
    }
#pragma unroll
    for (int kc = 0; kc < 32; ++kc)
        acc = MFMA16(av[kc], wf[kc], acc);

    bf16* drow = dst + ((size_t)(16 * bi + 4 * quad)) * 1024 + 16 * nj + l16;
#pragma unroll
    for (int rr = 0; rr < 4; ++rr)
        drow[(size_t)rr * 1024] = __float2bfloat16(acc[rr]);
}

// ---------------------------------------------------------------------------
// Fix-up:  UA[(c*16+j)*64 + b][n] += sum_k CIN[c*64+b][k] * P_{j+1}[n][k]
// dbuf-prefetch structure; per-z-slice T1 swizzle.  grid (16,8,16).
// ---------------------------------------------------------------------------
__global__ __launch_bounds__(256) void fixup_k(
    const bf16* __restrict__ CIN, const bf16* __restrict__ PBase,
    bf16* __restrict__ UA)
{
    __shared__ __align__(16) bf16 lA[2][128 * 64];
    __shared__ __align__(16) bf16 lB[2][128 * 64];
    const int tid  = threadIdx.x;
    const int lane = tid & 63, wv = tid >> 6;
    const int wm = wv & 1, wn = wv >> 1;
    const int quad = lane >> 4, l16 = lane & 15;

    const int lid = blockIdx.y * 16 + blockIdx.x;   // 0..127 within z-slice
    const int wid = (lid & 7) * 16 + (lid >> 3);    // XCD-contiguous (128/8 = 16)
    const int m0 = (wid >> 3) * 128;
    const int n0 = (wid & 7) * 128;

    const int j = blockIdx.z;
    const bf16* Bt = PBase + (size_t)j * 1048576;
    const int sr = lane >> 3;
    const int sc = ((lane & 7) ^ sr) * 8;

#define STAGE_AB(buf, ko) do { \
    _Pragma("unroll") \
    for (int qi = 0; qi < 4; ++qi) { \
        const int q = wv * 4 + qi; \
        GLL16(CIN + (size_t)(m0 + q * 8 + sr) * 1024 + (ko) + sc, (char*)lA[buf] + q * 1024); \
        GLL16(Bt  + (size_t)(n0 + q * 8 + sr) * 1024 + (ko) + sc, (char*)lB[buf] + q * 1024); \
    } } while (0)

    f32x4 acc[4][4] = {};
    STAGE_AB(0, 0);
    __syncthreads();
    int cur = 0;
    for (int t = 0; t < 16; ++t) {
        const int nxt = cur ^ 1;
        if (t < 15) STAGE_AB(nxt, (t + 1) * 64);
#pragma unroll
        for (int kc = 0; kc < 2; ++kc) {
            s16x8 af[4], bg[4];
#pragma unroll
            for (int mt = 0; mt < 4; ++mt) {
                const int r = 64 * wm + 16 * mt + l16;
                const int c = kc * 4 + quad;
                af[mt] = *(const s16x8*)((const char*)lA[cur] + r * 128 + ((c ^ (r & 7)) * 16));
            }
#pragma unroll
            for (int nt = 0; nt < 4; ++nt) {
                const int r = 64 * wn + 16 * nt + l16;
                const int c = kc * 4 + quad;
                bg[nt] = *(const s16x8*)((const char*)lB[cur] + r * 128 + ((c ^ (r & 7)) * 16));
            }
#pragma unroll
            for (int mt = 0; mt < 4; ++mt)
#pragma unroll
                for (int nt = 0; nt < 4; ++nt)
                    acc[mt][nt] = MFMA16(af[mt], bg[nt], acc[mt][nt]);
        }
        __syncthreads();
        cur = nxt;
    }
#undef STAGE_AB
#pragma unroll
    for (int mt = 0; mt < 4; ++mt)
#pragma unroll
        for (int r = 0; r < 4; ++r) {
            const int vm = m0 + 64 * wm + 16 * mt + 4 * quad + r;   // c*64 + b
            const size_t grow = (size_t)(((vm >> 6) * 16 + j) * 64 + (vm & 63));
#pragma unroll
            for (int nt = 0; nt < 4; ++nt) {
                const int n = n0 + 64 * wn + 16 * nt + l16;
                bf16* p = UA + grow * 1024 + n;
                *p = __float2bfloat16(acc[mt][nt][r] + __bfloat162float(*p));
            }
        }
}

// ---------------------------------------------------------------------------
// Blocked linear scan, S=16 chunk, G=32 chunks (see round-1 derivation).
// ---------------------------------------------------------------------------
extern "C" void kernel_launch(void* const* d_in, const int* in_sizes, int n_in,
                              void* d_out, int out_size, void* d_ws, size_t ws_size,
                              hipStream_t stream) {
    const float* X   = (const float*)d_in[0];   // [64,512,1024] f32
    const float* Wax = (const float*)d_in[1];   // [1024,1024]   f32
    const float* Waa = (const float*)d_in[2];   // [1024,1024]   f32
    const float* ba  = (const float*)d_in[3];   // [1024]        f32
    const float* Wy  = (const float*)d_in[4];   // [1024,1024]   f32
    const float* by  = (const float*)d_in[5];   // [1024]        f32

    char* ws = (char*)d_ws;
    bf16* UA   = (bf16*)ws;                       // 64 MB: [512][64][1024]
    bf16* PB   = (bf16*)(ws + 67108864);          // 32 MB: PB[k] = W^{k+1}, k=0..15
    bf16* Waxb = (bf16*)(ws + 100663296);         // 2 MB
    bf16* Wyb  = (bf16*)(ws + 102760448);         // 2 MB
    bf16* CIN  = (bf16*)(ws + 104857600);         // 4 MB: [32][64][1024] carry-in per chunk
    bf16* Tb   = CIN;                             // 2 MB transpose scratch (dead before carries)
    const size_t MM = 1048576;                    // elems per 1024x1024 matrix

    const int NW = 1024 * 1024;
    cvt_bf16<<<dim3(NW / 1024), dim3(256), 0, stream>>>(Wax, Waxb, NW);
    cvt_bf16<<<dim3(NW / 1024), dim3(256), 0, stream>>>(Waa, PB,   NW);   // PB[0] = W
    cvt_bf16<<<dim3(NW / 1024), dim3(256), 0, stream>>>(Wy,  Wyb,  NW);

    dim3 grid(256, 8), blk(256);
    // Phase A: U = X @ Wax^T + ba   (f32 A-operand, rows b*512+t -> t*64+b, bf16 out)
    gemm_bt<true, false, 1><<<grid, blk, 0, stream>>>(X, Waxb, ba, UA);

    // Powers of W (log-depth; powers commute so only P_{2^k}^T is ever needed):
    transpose_bf16<<<dim3(16, 16), blk, 0, stream>>>(PB, Tb);              // W^T
    powmul<<<dim3(8, 8, 1), blk, 0, stream>>>(PB, Tb, PB + 1 * MM);        // P2 = W*W
    transpose_bf16<<<dim3(16, 16), blk, 0, stream>>>(PB + 1 * MM, Tb);     // P2^T
    powmul<<<dim3(8, 8, 2), blk, 0, stream>>>(PB, Tb, PB + 2 * MM);        // P3,P4 = {P1,P2}*P2
    transpose_bf16<<<dim3(16, 16), blk, 0, stream>>>(PB + 3 * MM, Tb);     // P4^T
    powmul<<<dim3(8, 8, 4), blk, 0, stream>>>(PB, Tb, PB + 4 * MM);        // P5..P8 = {P1..P4}*P4
    transpose_bf16<<<dim3(16, 16), blk, 0, stream>>>(PB + 7 * MM, Tb);     // P8^T
    powmul<<<dim3(8, 8, 8), blk, 0, stream>>>(PB, Tb, PB + 8 * MM);        // P9..P16 = {P1..P8}*P8

    // Local chunk scans: depth 15, all 32 chunks in parallel per launch.
    for (int j = 1; j < 16; ++j)
        local_step<<<dim3(32, 8), blk, 0, stream>>>(PB, UA, j);

    // Carry scan over chunk ends: CIN[c] = A_end[c-1]; CIN[0] = 0.
    zero_bf16<<<dim3(32), dim3(256), 0, stream>>>(CIN, 65536);
    for (int c = 1; c < 32; ++c)
        carry_step<<<dim3(256), dim3(64), 0, stream>>>(
            PB + 15 * MM,
            UA  + (size_t)((c - 1) * 16 + 15) * 65536,
            CIN + (size_t)(c - 1) * 65536,
            CIN + (size_t)c * 65536);

    // Fix-up: UA[c*16+j] += CIN[c] @ (W^{j+1})^T, one parallel launch.
    fixup_k<<<dim3(16, 8, 16), blk, 0, stream>>>(CIN, PB, UA);

    // Phase C: Y = A @ Wy^T + by    (rows t*64+b -> b*512+t, f32 out to d_out)
    gemm_bt<false, true, 2><<<grid, blk, 0, stream>>>(UA, Wyb, by, (float*)d_out);
}

// Round 4
// 874.323 us; speedup vs baseline: 1.1067x; 1.1067x over previous
//
#include <hip/hip_runtime.h>
#include <hip/hip_bf16.h>
#include <stdint.h>
#include <stddef.h>

using bf16 = __hip_bfloat16;
typedef short s16x8 __attribute__((ext_vector_type(8)));   // 8 bf16 = one MFMA frag (4 VGPRs)
typedef float f32x4 __attribute__((ext_vector_type(4)));

#define MFMA16(a, b, c) __builtin_amdgcn_mfma_f32_16x16x32_bf16((a), (b), (c), 0, 0, 0)

typedef __attribute__((address_space(1))) void gvoid;
typedef __attribute__((address_space(3))) void lvoid;
// global -> LDS direct copy, 16B per lane; LDS dest = wave-uniform base + lane*16
#define GLL16(gp, lp) __builtin_amdgcn_global_load_lds((gvoid*)(void*)(gp), (lvoid*)(lp), 16, 0, 0)

__device__ __forceinline__ short f2bf(float x) {
    bf16 h = __float2bfloat16(x);
    return __builtin_bit_cast(short, h);
}

// f32 -> bf16 elementwise, n % 1024 == 0, grid*block*4 == n
__global__ void cvt_bf16(const float* __restrict__ in, bf16* __restrict__ out, int n) {
    int i = (blockIdx.x * blockDim.x + threadIdx.x) * 4;
    if (i < n) {
        float4 v = *(const float4*)(in + i);
        out[i + 0] = __float2bfloat16(v.x);
        out[i + 1] = __float2bfloat16(v.y);
        out[i + 2] = __float2bfloat16(v.z);
        out[i + 3] = __float2bfloat16(v.w);
    }
}

// zero n bf16 (n % 2048 == 0), grid*block*8 == n
__global__ void zero_bf16(bf16* __restrict__ p, int n) {
    int i = (blockIdx.x * blockDim.x + threadIdx.x) * 8;
    if (i < n) {
        s16x8 z = {0, 0, 0, 0, 0, 0, 0, 0};
        *(s16x8*)(p + i) = z;
    }
}

// 1024x1024 bf16 transpose: out = in^T.  grid (16,16), block 256.
__global__ __launch_bounds__(256) void transpose_bf16(
    const bf16* __restrict__ in, bf16* __restrict__ out)
{
    __shared__ bf16 t[64][72];
    const int bx = blockIdx.x * 64, by = blockIdx.y * 64;
    const int tid = threadIdx.x;
#pragma unroll
    for (int i = 0; i < 2; ++i) {
        const int r = (tid >> 3) + i * 32, c = (tid & 7) * 8;
        *(s16x8*)&t[r][c] = *(const s16x8*)(in + (size_t)(bx + r) * 1024 + by + c);
    }
    __syncthreads();
#pragma unroll
    for (int i = 0; i < 2; ++i) {
        const int r = (tid >> 3) + i * 32, c = (tid & 7) * 8;
        s16x8 v;
#pragma unroll
        for (int k = 0; k < 8; ++k) v[k] = __builtin_bit_cast(short, t[c + k][r]);
        *(s16x8*)(out + (size_t)(by + r) * 1024 + bx + c) = v;
    }
}

// ---------------------------------------------------------------------------
// 256x256-tile GEMM (m248-verified regime: 256^2 + 2-phase dbuf @ K=1024
// = 655-666 TF vs our 128^2's 354):  C[om(m)][n] = bias[n] + sum_k A[m][k]*Bt[n][k]
// 512 threads = 8 waves (2m x 4n), per-wave 128x64 out, BK=64, LDS 128 KB
// (1 block/CU; per-step MFMA work 4x the 128^2 tile amortizes barrier drain).
// Prefetch: stage K-step t+1 BEFORE computing t, one __syncthreads per step.
// A_F32: A loaded global->reg early, converted + ds_written after MFMAs (T14).
// T1 swizzle: 512 blocks -> XCD-contiguous bands, n-tile fastest.
// ---------------------------------------------------------------------------
template<bool A_F32, bool OUT_F32, int REMAP>
__global__ __launch_bounds__(512, 2) void gemm_bt256(
    const void* __restrict__ Ap, const bf16* __restrict__ Bt,
    const float* __restrict__ bias, void* __restrict__ Cp)
{
    __shared__ __align__(16) bf16 lA[2][256 * 64];
    __shared__ __align__(16) bf16 lB[2][256 * 64];

    const int tid  = threadIdx.x;
    const int lane = tid & 63, wv = tid >> 6;        // wv 0..7
    const int wm = wv >> 2, wn = wv & 3;             // 2 x 4 wave grid
    const int quad = lane >> 4, l16 = lane & 15;

    // XCD-aware swizzle: 512 blocks, 64 per XCD, n-tile fastest per m-slab.
    const int lid = blockIdx.y * 128 + blockIdx.x;   // grid (128,4), x fastest
    const int wid = (lid & 7) * 64 + (lid >> 3);     // bijective, 512 % 8 == 0
    const int m0 = (wid >> 2) * 256;                 // 128 m-tiles
    const int n0 = (wid & 3) * 256;                  // 4 n-tiles

    const int sr = lane >> 3;
    const int sc = ((lane & 7) ^ sr) * 8;   // element offset of swizzled 16B chunk
    const int ar = tid >> 1;                // A_F32: row 0..255
    const int ah = tid & 1;

    const float* Af = (const float*)Ap;
    const bf16*  Ab = (const bf16*)Ap;

    f32x4 acc[8][4] = {};
    float4 vr[4][2];          // f32-A register staging (A_F32 only)

#define STAGE_B6(buf, ko) do { \
    _Pragma("unroll") \
    for (int qi = 0; qi < 4; ++qi) { \
        const int q = wv * 4 + qi; \
        GLL16(Bt + (size_t)(n0 + q * 8 + sr) * 1024 + (ko) + sc, (char*)lB[buf] + q * 1024); \
    } } while (0)
#define STAGE_A_BF6(buf, ko) do { \
    _Pragma("unroll") \
    for (int qi = 0; qi < 4; ++qi) { \
        const int q = wv * 4 + qi; \
        GLL16(Ab + (size_t)(m0 + q * 8 + sr) * 1024 + (ko) + sc, (char*)lA[buf] + q * 1024); \
    } } while (0)
#define LOAD_A_F326(ko) do { \
    _Pragma("unroll") \
    for (int i = 0; i < 4; ++i) { \
        const int c = ah * 4 + i; \
        const float* srcp = Af + (size_t)(m0 + ar) * 1024 + (ko) + c * 8; \
        vr[i][0] = *(const float4*)(srcp); \
        vr[i][1] = *(const float4*)(srcp + 4); \
    } } while (0)
#define WRITE_A_F326(buf) do { \
    _Pragma("unroll") \
    for (int i = 0; i < 4; ++i) { \
        const int c = ah * 4 + i; \
        s16x8 w; \
        w[0] = f2bf(vr[i][0].x); w[1] = f2bf(vr[i][0].y); w[2] = f2bf(vr[i][0].z); w[3] = f2bf(vr[i][0].w); \
        w[4] = f2bf(vr[i][1].x); w[5] = f2bf(vr[i][1].y); w[6] = f2bf(vr[i][1].z); w[7] = f2bf(vr[i][1].w); \
        *(s16x8*)((char*)lA[buf] + ar * 128 + ((c ^ (ar & 7)) << 4)) = w; \
    } } while (0)

    // prologue: stage ko=0 into buffer 0
    if constexpr (A_F32) { LOAD_A_F326(0); WRITE_A_F326(0); }
    else                 { STAGE_A_BF6(0, 0); }
    STAGE_B6(0, 0);
    __syncthreads();

    int cur = 0;
    for (int t = 0; t < 16; ++t) {
        const int nxt = cur ^ 1;
        if (t < 15) {
            const int ko = (t + 1) * 64;
            if constexpr (A_F32) LOAD_A_F326(ko);
            else                 STAGE_A_BF6(nxt, ko);
            STAGE_B6(nxt, ko);
        }
#pragma unroll
        for (int kc = 0; kc < 2; ++kc) {
            s16x8 af[8], bg[4];
#pragma unroll
            for (int mt = 0; mt < 8; ++mt) {
                const int r = 128 * wm + 16 * mt + l16;
                const int c = kc * 4 + quad;
                af[mt] = *(const s16x8*)((const char*)lA[cur] + r * 128 + ((c ^ (r & 7)) * 16));
            }
#pragma unroll
            for (int nt = 0; nt < 4; ++nt) {
                const int r = 64 * wn + 16 * nt + l16;
                const int c = kc * 4 + quad;
                bg[nt] = *(const s16x8*)((const char*)lB[cur] + r * 128 + ((c ^ (r & 7)) * 16));
            }
#pragma unroll
            for (int mt = 0; mt < 8; ++mt)
#pragma unroll
                for (int nt = 0; nt < 4; ++nt)
                    acc[mt][nt] = MFMA16(af[mt], bg[nt], acc[mt][nt]);
        }
        if constexpr (A_F32) { if (t < 15) WRITE_A_F326(nxt); }
        __syncthreads();
        cur = nxt;
    }
#undef STAGE_B6
#undef STAGE_A_BF6
#undef LOAD_A_F326
#undef WRITE_A_F326

    float bv[4];
#pragma unroll
    for (int nt = 0; nt < 4; ++nt)
        bv[nt] = bias[n0 + 64 * wn + 16 * nt + l16];

    // D layout: row = quad*4 + reg, col = lane&15  (m89/m91-verified)
#pragma unroll
    for (int mt = 0; mt < 8; ++mt) {
#pragma unroll
        for (int r = 0; r < 4; ++r) {
            const int m = m0 + 128 * wm + 16 * mt + 4 * quad + r;
            int om = m;
            if constexpr (REMAP == 1)      om = ((m & 511) << 6) | (m >> 9); // b*512+t -> t*64+b
            else if constexpr (REMAP == 2) om = ((m & 63) << 9) | (m >> 6);  // t*64+b -> b*512+t
#pragma unroll
            for (int nt = 0; nt < 4; ++nt) {
                const int n = n0 + 64 * wn + 16 * nt + l16;
                const float val = acc[mt][nt][r] + bv[nt];
                if constexpr (OUT_F32) ((float*)Cp)[(size_t)om * 1024 + n] = val;
                else ((bf16*)Cp)[(size_t)om * 1024 + n] = __float2bfloat16(val);
            }
        }
    }
}

// ---------------------------------------------------------------------------
// Fix-up, 256^2 structure:  UA[(c*16+j)*64+b][n] += sum_k CIN[c*64+b][k]*P_{j+1}[n][k]
// grid (8,4,16); per-z-slice T1 swizzle (32 blocks, 4 per XCD, n fastest).
// ---------------------------------------------------------------------------
__global__ __launch_bounds__(512, 2) void fixup_k256(
    const bf16* __restrict__ CIN, const bf16* __restrict__ PBase,
    bf16* __restrict__ UA)
{
    __shared__ __align__(16) bf16 lA[2][256 * 64];
    __shared__ __align__(16) bf16 lB[2][256 * 64];
    const int tid  = threadIdx.x;
    const int lane = tid & 63, wv = tid >> 6;
    const int wm = wv >> 2, wn = wv & 3;
    const int quad = lane >> 4, l16 = lane & 15;

    const int lid = blockIdx.y * 8 + blockIdx.x;    // 0..31 within z-slice
    const int wid = (lid & 7) * 4 + (lid >> 3);     // bijective, 32 % 8 == 0
    const int m0 = (wid >> 2) * 256;                // 8 m-tiles
    const int n0 = (wid & 3) * 256;                 // 4 n-tiles

    const int j = blockIdx.z;
    const bf16* Bt = PBase + (size_t)j * 1048576;
    const int sr = lane >> 3;
    const int sc = ((lane & 7) ^ sr) * 8;

#define STAGE_AB6(buf, ko) do { \
    _Pragma("unroll") \
    for (int qi = 0; qi < 4; ++qi) { \
        const int q = wv * 4 + qi; \
        GLL16(CIN + (size_t)(m0 + q * 8 + sr) * 1024 + (ko) + sc, (char*)lA[buf] + q * 1024); \
        GLL16(Bt  + (size_t)(n0 + q * 8 + sr) * 1024 + (ko) + sc, (char*)lB[buf] + q * 1024); \
    } } while (0)

    f32x4 acc[8][4] = {};
    STAGE_AB6(0, 0);
    __syncthreads();
    int cur = 0;
    for (int t = 0; t < 16; ++t) {
        const int nxt = cur ^ 1;
        if (t < 15) STAGE_AB6(nxt, (t + 1) * 64);
#pragma unroll
        for (int kc = 0; kc < 2; ++kc) {
            s16x8 af[8], bg[4];
#pragma unroll
            for (int mt = 0; mt < 8; ++mt) {
                const int r = 128 * wm + 16 * mt + l16;
                const int c = kc * 4 + quad;
                af[mt] = *(const s16x8*)((const char*)lA[cur] + r * 128 + ((c ^ (r & 7)) * 16));
            }
#pragma unroll
            for (int nt = 0; nt < 4; ++nt) {
                const int r = 64 * wn + 16 * nt + l16;
                const int c = kc * 4 + quad;
                bg[nt] = *(const s16x8*)((const char*)lB[cur] + r * 128 + ((c ^ (r & 7)) * 16));
            }
#pragma unroll
            for (int mt = 0; mt < 8; ++mt)
#pragma unroll
                for (int nt = 0; nt < 4; ++nt)
                    acc[mt][nt] = MFMA16(af[mt], bg[nt], acc[mt][nt]);
        }
        __syncthreads();
        cur = nxt;
    }
#undef STAGE_AB6
#pragma unroll
    for (int mt = 0; mt < 8; ++mt)
#pragma unroll
        for (int r = 0; r < 4; ++r) {
            const int vm = m0 + 128 * wm + 16 * mt + 4 * quad + r;   // c*64 + b
            const size_t grow = (size_t)(((vm >> 6) * 16 + j) * 64 + (vm & 63));
#pragma unroll
            for (int nt = 0; nt < 4; ++nt) {
                const int n = n0 + 64 * wn + 16 * nt + l16;
                bf16* p = UA + grow * 1024 + n;
                *p = __float2bfloat16(acc[mt][nt][r] + __bfloat162float(*p));
            }
        }
}

// ---------------------------------------------------------------------------
// Power chain: D[z] = A[z] @ Bt^T.  dbuf-prefetch 128^2 (latency-bound, small
// grid -- dbuf helped these in round 3).  grid (8,8,z).
// ---------------------------------------------------------------------------
__global__ __launch_bounds__(256) void powmul(
    const bf16* __restrict__ Abase, const bf16* __restrict__ Bt,
    bf16* __restrict__ Dbase)
{
    __shared__ __align__(16) bf16 lA[2][128 * 64];
    __shared__ __align__(16) bf16 lB[2][128 * 64];
    const int tid  = threadIdx.x;
    const int lane = tid & 63, wv = tid >> 6;
    const int wm = wv & 1, wn = wv >> 1;
    const int quad = lane >> 4, l16 = lane & 15;
    const int m0 = blockIdx.x * 128, n0 = blockIdx.y * 128;
    const bf16* A = Abase + (size_t)blockIdx.z * 1048576;
    bf16* D       = Dbase + (size_t)blockIdx.z * 1048576;
    const int sr = lane >> 3;
    const int sc = ((lane & 7) ^ sr) * 8;

#define STAGE_AB(buf, ko) do { \
    _Pragma("unroll") \
    for (int qi = 0; qi < 4; ++qi) { \
        const int q = wv * 4 + qi; \
        GLL16(A  + (size_t)(m0 + q * 8 + sr) * 1024 + (ko) + sc, (char*)lA[buf] + q * 1024); \
        GLL16(Bt + (size_t)(n0 + q * 8 + sr) * 1024 + (ko) + sc, (char*)lB[buf] + q * 1024); \
    } } while (0)

    f32x4 acc[4][4] = {};
    STAGE_AB(0, 0);
    __syncthreads();
    int cur = 0;
    for (int t = 0; t < 16; ++t) {
        const int nxt = cur ^ 1;
        if (t < 15) STAGE_AB(nxt, (t + 1) * 64);
#pragma unroll
        for (int kc = 0; kc < 2; ++kc) {
            s16x8 af[4], bg[4];
#pragma unroll
            for (int mt = 0; mt < 4; ++mt) {
                const int r = 64 * wm + 16 * mt + l16;
                const int c = kc * 4 + quad;
                af[mt] = *(const s16x8*)((const char*)lA[cur] + r * 128 + ((c ^ (r & 7)) * 16));
            }
#pragma unroll
            for (int nt = 0; nt < 4; ++nt) {
                const int r = 64 * wn + 16 * nt + l16;
                const int c = kc * 4 + quad;
                bg[nt] = *(const s16x8*)((const char*)lB[cur] + r * 128 + ((c ^ (r & 7)) * 16));
            }
#pragma unroll
            for (int mt = 0; mt < 4; ++mt)
#pragma unroll
                for (int nt = 0; nt < 4; ++nt)
                    acc[mt][nt] = MFMA16(af[mt], bg[nt], acc[mt][nt]);
        }
        __syncthreads();
        cur = nxt;
    }
#undef STAGE_AB
#pragma unroll
    for (int mt = 0; mt < 4; ++mt)
#pragma unroll
        for (int r = 0; r < 4; ++r) {
            const int m = m0 + 64 * wm + 16 * mt + 4 * quad + r;
#pragma unroll
            for (int nt = 0; nt < 4; ++nt) {
                const int n = n0 + 64 * wn + 16 * nt + l16;
                D[(size_t)m * 1024 + n] = __float2bfloat16(acc[mt][nt][r]);
            }
        }
}

// ---------------------------------------------------------------------------
// Local scan step j: rows t = c*16+j:  UA[t] += UA[t-1] @ Waa^T
// dbuf-prefetch (helped in round 3: latency-bound, 1 block/CU). grid (32, 8).
// ---------------------------------------------------------------------------
__global__ __launch_bounds__(256) void local_step(
    const bf16* __restrict__ Bt, bf16* __restrict__ UA, int j)
{
    __shared__ __align__(16) bf16 lA[2][64 * 64];
    __shared__ __align__(16) bf16 lB[2][128 * 64];
    const int tid = threadIdx.x;
    const int lane = tid & 63, wv = tid >> 6;
    const int quad = lane >> 4, l16 = lane & 15;
    const int n0 = blockIdx.y * 128;
    const int t_ = blockIdx.x * 16 + j;
    const bf16* src = UA + (size_t)(t_ - 1) * 64 * 1024;
    bf16* dst       = UA + (size_t)t_ * 64 * 1024;
    const int sr = lane >> 3;
    const int sc = ((lane & 7) ^ sr) * 8;

#define STAGE_AB(buf, ko) do { \
    _Pragma("unroll") \
    for (int qi = 0; qi < 2; ++qi) { \
        const int q = wv * 2 + qi; \
        GLL16(src + (size_t)(q * 8 + sr) * 1024 + (ko) + sc, (char*)lA[buf] + q * 1024); \
    } \
    _Pragma("unroll") \
    for (int qi = 0; qi < 4; ++qi) { \
        const int q = wv * 4 + qi; \
        GLL16(Bt + (size_t)(n0 + q * 8 + sr) * 1024 + (ko) + sc, (char*)lB[buf] + q * 1024); \
    } } while (0)

    f32x4 acc[4][2] = {};
    STAGE_AB(0, 0);
    __syncthreads();
    int cur = 0;
    for (int t = 0; t < 16; ++t) {
        const int nxt = cur ^ 1;
        if (t < 15) STAGE_AB(nxt, (t + 1) * 64);
#pragma unroll
        for (int kc = 0; kc < 2; ++kc) {
            s16x8 af[4], bg[2];
#pragma unroll
            for (int mt = 0; mt < 4; ++mt) {
                const int r = 16 * mt + l16;
                const int c = kc * 4 + quad;
                af[mt] = *(const s16x8*)((const char*)lA[cur] + r * 128 + ((c ^ (r & 7)) * 16));
            }
#pragma unroll
            for (int nt = 0; nt < 2; ++nt) {
                const int r = 32 * wv + 16 * nt + l16;
                const int c = kc * 4 + quad;
                bg[nt] = *(const s16x8*)((const char*)lB[cur] + r * 128 + ((c ^ (r & 7)) * 16));
            }
#pragma unroll
            for (int mt = 0; mt < 4; ++mt)
#pragma unroll
                for (int nt = 0; nt < 2; ++nt)
                    acc[mt][nt] = MFMA16(af[mt], bg[nt], acc[mt][nt]);
        }
        __syncthreads();
        cur = nxt;
    }
#undef STAGE_AB
#pragma unroll
    for (int mt = 0; mt < 4; ++mt)
#pragma unroll
        for (int r = 0; r < 4; ++r) {
            const int b = 16 * mt + 4 * quad + r;
#pragma unroll
            for (int nt = 0; nt < 2; ++nt) {
                const int n = n0 + 32 * wv + 16 * nt + l16;
                bf16* p = dst + (size_t)b * 1024 + n;
                *p = __float2bfloat16(acc[mt][nt][r] + __bfloat162float(*p));
            }
        }
}

// ---------------------------------------------------------------------------
// Carry step: dst[b][n] = lend[b][n] + sum_k src[b][k] * P16[n][k]
// Launch-latency floor; unchanged.  256 blocks x 1 wave.
// ---------------------------------------------------------------------------
__global__ __launch_bounds__(64, 1) void carry_step(
    const bf16* __restrict__ P16, const bf16* __restrict__ lend,
    const bf16* __restrict__ src, bf16* __restrict__ dst)
{
    const int lane = threadIdx.x;
    const int quad = lane >> 4, l16 = lane & 15;
    const int bi = blockIdx.x & 3, nj = blockIdx.x >> 2;

    const bf16* arow = src + ((size_t)(16 * bi + l16)) * 1024;
    const bf16* wrow = P16 + ((size_t)(16 * nj + l16)) * 1024;

    const bf16* urow = lend + ((size_t)(16 * bi + 4 * quad)) * 1024 + 16 * nj + l16;
    f32x4 acc;
#pragma unroll
    for (int rr = 0; rr < 4; ++rr)
        acc[rr] = __bfloat162float(urow[(size_t)rr * 1024]);

    s16x8 av[32], wf[32];
#pragma unroll
    for (int kc = 0; kc < 32; ++kc) {
        av[kc] = *(const s16x8*)(arow + kc * 32 + quad * 8);
        wf[kc] = *(const s16x8*)(wrow + kc * 32 + quad * 8);
    }
#pragma unroll
    for (int kc = 0; kc < 32; ++kc)
        acc = MFMA16(av[kc], wf[kc], acc);

    bf16* drow = dst + ((size_t)(16 * bi + 4 * quad)) * 1024 + 16 * nj + l16;
#pragma unroll
    for (int rr = 0; rr < 4; ++rr)
        drow[(size_t)rr * 1024] = __float2bfloat16(acc[rr]);
}

// ---------------------------------------------------------------------------
// Blocked linear scan, S=16 chunk, G=32 chunks (see round-1 derivation).
// ---------------------------------------------------------------------------
extern "C" void kernel_launch(void* const* d_in, const int* in_sizes, int n_in,
                              void* d_out, int out_size, void* d_ws, size_t ws_size,
                              hipStream_t stream) {
    const float* X   = (const float*)d_in[0];   // [64,512,1024] f32
    const float* Wax = (const float*)d_in[1];   // [1024,1024]   f32
    const float* Waa = (const float*)d_in[2];   // [1024,1024]   f32
    const float* ba  = (const float*)d_in[3];   // [1024]        f32
    const float* Wy  = (const float*)d_in[4];   // [1024,1024]   f32
    const float* by  = (const float*)d_in[5];   // [1024]        f32

    char* ws = (char*)d_ws;
    bf16* UA   = (bf16*)ws;                       // 64 MB: [512][64][1024]
    bf16* PB   = (bf16*)(ws + 67108864);          // 32 MB: PB[k] = W^{k+1}, k=0..15
    bf16* Waxb = (bf16*)(ws + 100663296);         // 2 MB
    bf16* Wyb  = (bf16*)(ws + 102760448);         // 2 MB
    bf16* CIN  = (bf16*)(ws + 104857600);         // 4 MB: [32][64][1024] carry-in per chunk
    bf16* Tb   = CIN;                             // 2 MB transpose scratch (dead before carries)
    const size_t MM = 1048576;                    // elems per 1024x1024 matrix

    const int NW = 1024 * 1024;
    cvt_bf16<<<dim3(NW / 1024), dim3(256), 0, stream>>>(Wax, Waxb, NW);
    cvt_bf16<<<dim3(NW / 1024), dim3(256), 0, stream>>>(Waa, PB,   NW);   // PB[0] = W
    cvt_bf16<<<dim3(NW / 1024), dim3(256), 0, stream>>>(Wy,  Wyb,  NW);

    dim3 gridG(128, 4), blk2(512), blk(256);
    // Phase A: U = X @ Wax^T + ba   (f32 A-operand, rows b*512+t -> t*64+b, bf16 out)
    gemm_bt256<true, false, 1><<<gridG, blk2, 0, stream>>>(X, Waxb, ba, UA);

    // Powers of W (log-depth; powers commute so only P_{2^k}^T is ever needed):
    transpose_bf16<<<dim3(16, 16), blk, 0, stream>>>(PB, Tb);              // W^T
    powmul<<<dim3(8, 8, 1), blk, 0, stream>>>(PB, Tb, PB + 1 * MM);        // P2 = W*W
    transpose_bf16<<<dim3(16, 16), blk, 0, stream>>>(PB + 1 * MM, Tb);     // P2^T
    powmul<<<dim3(8, 8, 2), blk, 0, stream>>>(PB, Tb, PB + 2 * MM);        // P3,P4 = {P1,P2}*P2
    transpose_bf16<<<dim3(16, 16), blk, 0, stream>>>(PB + 3 * MM, Tb);     // P4^T
    powmul<<<dim3(8, 8, 4), blk, 0, stream>>>(PB, Tb, PB + 4 * MM);        // P5..P8 = {P1..P4}*P4
    transpose_bf16<<<dim3(16, 16), blk, 0, stream>>>(PB + 7 * MM, Tb);     // P8^T
    powmul<<<dim3(8, 8, 8), blk, 0, stream>>>(PB, Tb, PB + 8 * MM);        // P9..P16 = {P1..P8}*P8

    // Local chunk scans: depth 15, all 32 chunks in parallel per launch.
    for (int j = 1; j < 16; ++j)
        local_step<<<dim3(32, 8), blk, 0, stream>>>(PB, UA, j);

    // Carry scan over chunk ends: CIN[c] = A_end[c-1]; CIN[0] = 0.
    zero_bf16<<<dim3(32), dim3(256), 0, stream>>>(CIN, 65536);
    for (int c = 1; c < 32; ++c)
        carry_step<<<dim3(256), dim3(64), 0, stream>>>(
            PB + 15 * MM,
            UA  + (size_t)((c - 1) * 16 + 15) * 65536,
            CIN + (size_t)(c - 1) * 65536,
            CIN + (size_t)c * 65536);

    // Fix-up: UA[c*16+j] += CIN[c] @ (W^{j+1})^T, one parallel launch.
    fixup_k256<<<dim3(8, 4, 16), blk2, 0, stream>>>(CIN, PB, UA);

    // Phase C: Y = A @ Wy^T + by    (rows t*64+b -> b*512+t, f32 out to d_out)
    gemm_bt256<false, true, 2><<<gridG, blk2, 0, stream>>>(UA, Wyb, by, (float*)d_out);
}

// Round 5
// 866.928 us; speedup vs baseline: 1.1161x; 1.0085x over previous
//
#include <hip/hip_runtime.h>
#include <hip/hip_bf16.h>
#include <stdint.h>
#include <stddef.h>

using bf16 = __hip_bfloat16;
typedef short s16x8 __attribute__((ext_vector_type(8)));   // 8 bf16 = one MFMA frag (4 VGPRs)
typedef float f32x4 __attribute__((ext_vector_type(4)));

#define MFMA16(a, b, c) __builtin_amdgcn_mfma_f32_16x16x32_bf16((a), (b), (c), 0, 0, 0)

typedef __attribute__((address_space(1))) void gvoid;
typedef __attribute__((address_space(3))) void lvoid;
// global -> LDS direct copy, 16B per lane; LDS dest = wave-uniform base + lane*16
#define GLL16(gp, lp) __builtin_amdgcn_global_load_lds((gvoid*)(void*)(gp), (lvoid*)(lp), 16, 0, 0)

__device__ __forceinline__ short f2bf(float x) {
    bf16 h = __float2bfloat16(x);
    return __builtin_bit_cast(short, h);
}

// f32 -> bf16 elementwise, n % 1024 == 0, grid*block*4 == n
__global__ void cvt_bf16(const float* __restrict__ in, bf16* __restrict__ out, int n) {
    int i = (blockIdx.x * blockDim.x + threadIdx.x) * 4;
    if (i < n) {
        float4 v = *(const float4*)(in + i);
        out[i + 0] = __float2bfloat16(v.x);
        out[i + 1] = __float2bfloat16(v.y);
        out[i + 2] = __float2bfloat16(v.z);
        out[i + 3] = __float2bfloat16(v.w);
    }
}

// zero n bf16 (n % 2048 == 0), grid*block*8 == n
__global__ void zero_bf16(bf16* __restrict__ p, int n) {
    int i = (blockIdx.x * blockDim.x + threadIdx.x) * 8;
    if (i < n) {
        s16x8 z = {0, 0, 0, 0, 0, 0, 0, 0};
        *(s16x8*)(p + i) = z;
    }
}

// 1024x1024 bf16 transpose: out = in^T.  grid (16,16), block 256.
__global__ __launch_bounds__(256) void transpose_bf16(
    const bf16* __restrict__ in, bf16* __restrict__ out)
{
    __shared__ bf16 t[64][72];
    const int bx = blockIdx.x * 64, by = blockIdx.y * 64;
    const int tid = threadIdx.x;
#pragma unroll
    for (int i = 0; i < 2; ++i) {
        const int r = (tid >> 3) + i * 32, c = (tid & 7) * 8;
        *(s16x8*)&t[r][c] = *(const s16x8*)(in + (size_t)(bx + r) * 1024 + by + c);
    }
    __syncthreads();
#pragma unroll
    for (int i = 0; i < 2; ++i) {
        const int r = (tid >> 3) + i * 32, c = (tid & 7) * 8;
        s16x8 v;
#pragma unroll
        for (int k = 0; k < 8; ++k) v[k] = __builtin_bit_cast(short, t[c + k][r]);
        *(s16x8*)(out + (size_t)(by + r) * 1024 + bx + c) = v;
    }
}

// ===========================================================================
// 8-phase counted-vmcnt 256^2 GEMM core (T3+T4+T5, m201-template port).
// Shared phase macros; bf16 A via GLL16.  K-tile = 64; 16 K-tiles.
// Per K-tile, 4 phases = C-quadrants (0,0),(0,1),(1,1),(1,0):
//   {ds_read subtile | stage 1 half-tile | s_barrier | setprio+16 MFMA | s_barrier}
// Staging ledger (per K-tile k, cur = k&1, nxt = cur^1):
//   p0: stage B-lo of k+1 -> nxt   (nxt fully dead: consumed in k-1)
//   p1: stage B-hi of k+1 -> nxt
//   p2: stage A-lo of k+2 -> cur   (cur.A-lo consumed at p0, barrier after)
//   p3: stage A-hi of k+2 -> cur   (cur.A-hi consumed at p2, barrier after)
//   p3 end: s_waitcnt vmcnt(4): queue = {A(k+1)x4, B(k+1)x4, A(k+2)x4};
//           oldest 8 = K-tile k+1 complete; A(k+2) stays in flight.
// Tail: k=14 skips A-stages + drains vmcnt(0); k=15 stages nothing.
// Raw s_barrier (no vmcnt drain); compiler manages lgkmcnt for ds_reads.
// ===========================================================================
#define G8_READ_AF(mh) do { _Pragma("unroll") \
    for (int mt = 0; mt < 4; ++mt) { _Pragma("unroll") \
        for (int kc = 0; kc < 2; ++kc) { \
            const int r = 128 * wm + 16 * ((mh) * 4 + mt) + l16; \
            const int c = kc * 4 + quad; \
            af[mt][kc] = *(const s16x8*)((const char*)lA[curb] + r * 128 + ((c ^ (r & 7)) * 16)); \
        } } } while (0)

#define G8_READ_BG(nh) do { _Pragma("unroll") \
    for (int nt = 0; nt < 2; ++nt) { _Pragma("unroll") \
        for (int kc = 0; kc < 2; ++kc) { \
            const int r = 64 * wn + 16 * ((nh) * 2 + nt) + l16; \
            const int c = kc * 4 + quad; \
            bg[nt][kc] = *(const s16x8*)((const char*)lB[curb] + r * 128 + ((c ^ (r & 7)) * 16)); \
        } } } while (0)

#define G8_MFMA_Q(mh, nh) do { \
    __builtin_amdgcn_s_setprio(1); \
    _Pragma("unroll") \
    for (int mt = 0; mt < 4; ++mt) \
        _Pragma("unroll") \
        for (int nt = 0; nt < 2; ++nt) \
            _Pragma("unroll") \
            for (int kc = 0; kc < 2; ++kc) \
                acc[(mh) * 4 + mt][(nh) * 2 + nt] = \
                    MFMA16(af[mt][kc], bg[nt][kc], acc[(mh) * 4 + mt][(nh) * 2 + nt]); \
    __builtin_amdgcn_s_setprio(0); \
    } while (0)

// half h (0: rows 0..127, 1: rows 128..255) of a 256x64 tile; 2 GLL16/wave
#define G8_STAGE_A(Asrc, buf, h, ko) do { _Pragma("unroll") \
    for (int qi = 0; qi < 2; ++qi) { \
        const int q = (h) * 16 + wv * 2 + qi; \
        GLL16(Asrc + (size_t)(m0 + q * 8 + sr) * 1024 + (ko) + sc, (char*)lA[buf] + q * 1024); \
    } } while (0)
#define G8_STAGE_B(Bsrc, buf, h, ko) do { _Pragma("unroll") \
    for (int qi = 0; qi < 2; ++qi) { \
        const int q = (h) * 16 + wv * 2 + qi; \
        GLL16(Bsrc + (size_t)(n0 + q * 8 + sr) * 1024 + (ko) + sc, (char*)lB[buf] + q * 1024); \
    } } while (0)

#define G8_KLOOP(Asrc, Bsrc) \
    /* prologue: K-tile 0 (A+B) + K-tile 1 A-halves; vmcnt(4) lands K-tile 0 */ \
    G8_STAGE_A(Asrc, 0, 0, 0);  G8_STAGE_A(Asrc, 0, 1, 0); \
    G8_STAGE_B(Bsrc, 0, 0, 0);  G8_STAGE_B(Bsrc, 0, 1, 0); \
    G8_STAGE_A(Asrc, 1, 0, 64); G8_STAGE_A(Asrc, 1, 1, 64); \
    asm volatile("s_waitcnt vmcnt(4)" ::: "memory"); \
    __builtin_amdgcn_s_barrier(); \
    for (int k = 0; k < 16; ++k) { \
        const int nxtb = curb ^ 1; \
        const int ko1 = (k + 1) * 64, ko2 = (k + 2) * 64; \
        /* p0: quadrant (0,0) */ \
        G8_READ_AF(0); G8_READ_BG(0); \
        if (k < 15) G8_STAGE_B(Bsrc, nxtb, 0, ko1); \
        __builtin_amdgcn_s_barrier(); \
        G8_MFMA_Q(0, 0); \
        __builtin_amdgcn_s_barrier(); \
        /* p1: quadrant (0,1) */ \
        G8_READ_BG(1); \
        if (k < 15) G8_STAGE_B(Bsrc, nxtb, 1, ko1); \
        __builtin_amdgcn_s_barrier(); \
        G8_MFMA_Q(0, 1); \
        __builtin_amdgcn_s_barrier(); \
        /* p2: quadrant (1,1) */ \
        G8_READ_AF(1); \
        if (k < 14) G8_STAGE_A(Asrc, curb, 0, ko2); \
        __builtin_amdgcn_s_barrier(); \
        G8_MFMA_Q(1, 1); \
        __builtin_amdgcn_s_barrier(); \
        /* p3: quadrant (1,0) */ \
        G8_READ_BG(0); \
        if (k < 14) G8_STAGE_A(Asrc, curb, 1, ko2); \
        __builtin_amdgcn_s_barrier(); \
        G8_MFMA_Q(1, 0); \
        if (k < 14)       { asm volatile("s_waitcnt vmcnt(4)" ::: "memory"); } \
        else if (k == 14) { asm volatile("s_waitcnt vmcnt(0)" ::: "memory"); } \
        __builtin_amdgcn_s_barrier(); \
        curb = nxtb; \
    }

// ---------------------------------------------------------------------------
// 8-phase GEMM:  C[om(m)][n] = bias[n] + sum_k A[m][k] * Bt[n][k]  (bf16 A)
// 512 thr = 8 waves (2m x 4n); per-wave 128x64 out.  T1 swizzle: grid (128,4).
// ---------------------------------------------------------------------------
template<bool OUT_F32, int REMAP>
__global__ __launch_bounds__(512, 2) void gemm8(
    const bf16* __restrict__ Ab, const bf16* __restrict__ Bt,
    const float* __restrict__ bias, void* __restrict__ Cp)
{
    __shared__ __align__(16) bf16 lA[2][256 * 64];
    __shared__ __align__(16) bf16 lB[2][256 * 64];

    const int tid  = threadIdx.x;
    const int lane = tid & 63, wv = tid >> 6;
    const int wm = wv >> 2, wn = wv & 3;
    const int quad = lane >> 4, l16 = lane & 15;

    const int lid = blockIdx.y * 128 + blockIdx.x;   // grid (128,4)
    const int wid = (lid & 7) * 64 + (lid >> 3);     // bijective, 512 % 8 == 0
    const int m0 = (wid >> 2) * 256;
    const int n0 = (wid & 3) * 256;

    const int sr = lane >> 3;
    const int sc = ((lane & 7) ^ sr) * 8;

    f32x4 acc[8][4] = {};
    s16x8 af[4][2], bg[2][2];
    int curb = 0;

    G8_KLOOP(Ab, Bt)

    float bv[4];
#pragma unroll
    for (int nt = 0; nt < 4; ++nt)
        bv[nt] = bias[n0 + 64 * wn + 16 * nt + l16];

#pragma unroll
    for (int mt = 0; mt < 8; ++mt) {
#pragma unroll
        for (int r = 0; r < 4; ++r) {
            const int m = m0 + 128 * wm + 16 * mt + 4 * quad + r;
            int om = m;
            if constexpr (REMAP == 1)      om = ((m & 511) << 6) | (m >> 9);
            else if constexpr (REMAP == 2) om = ((m & 63) << 9) | (m >> 6);
#pragma unroll
            for (int nt = 0; nt < 4; ++nt) {
                const int n = n0 + 64 * wn + 16 * nt + l16;
                const float val = acc[mt][nt][r] + bv[nt];
                if constexpr (OUT_F32) ((float*)Cp)[(size_t)om * 1024 + n] = val;
                else ((bf16*)Cp)[(size_t)om * 1024 + n] = __float2bfloat16(val);
            }
        }
    }
}

// ---------------------------------------------------------------------------
// 8-phase fix-up: UA[(c*16+j)*64+b][n] += sum_k CIN[c*64+b][k] * P_{j+1}[n][k]
// grid (8,4,16); per-z-slice T1 swizzle; RMW epilogue with row remap.
// ---------------------------------------------------------------------------
__global__ __launch_bounds__(512, 2) void fixup8(
    const bf16* __restrict__ CIN, const bf16* __restrict__ PBase,
    bf16* __restrict__ UA)
{
    __shared__ __align__(16) bf16 lA[2][256 * 64];
    __shared__ __align__(16) bf16 lB[2][256 * 64];

    const int tid  = threadIdx.x;
    const int lane = tid & 63, wv = tid >> 6;
    const int wm = wv >> 2, wn = wv & 3;
    const int quad = lane >> 4, l16 = lane & 15;

    const int lid = blockIdx.y * 8 + blockIdx.x;    // 0..31 within z-slice
    const int wid = (lid & 7) * 4 + (lid >> 3);     // bijective, 32 % 8 == 0
    const int m0 = (wid >> 2) * 256;
    const int n0 = (wid & 3) * 256;

    const int j = blockIdx.z;
    const bf16* Bt = PBase + (size_t)j * 1048576;
    const int sr = lane >> 3;
    const int sc = ((lane & 7) ^ sr) * 8;

    f32x4 acc[8][4] = {};
    s16x8 af[4][2], bg[2][2];
    int curb = 0;

    G8_KLOOP(CIN, Bt)

#pragma unroll
    for (int mt = 0; mt < 8; ++mt)
#pragma unroll
        for (int r = 0; r < 4; ++r) {
            const int vm = m0 + 128 * wm + 16 * mt + 4 * quad + r;   // c*64 + b
            const size_t grow = (size_t)(((vm >> 6) * 16 + j) * 64 + (vm & 63));
#pragma unroll
            for (int nt = 0; nt < 4; ++nt) {
                const int n = n0 + 64 * wn + 16 * nt + l16;
                bf16* p = UA + grow * 1024 + n;
                *p = __float2bfloat16(acc[mt][nt][r] + __bfloat162float(*p));
            }
        }
}

// ---------------------------------------------------------------------------
// Phase A GEMM (f32 A-operand): 256^2 2-phase dbuf (round-4 verified).
// Ports to 8-phase next round once the bf16 8-phase core is harness-verified.
// ---------------------------------------------------------------------------
__global__ __launch_bounds__(512, 2) void gemm_bt256_af32(
    const float* __restrict__ Af, const bf16* __restrict__ Bt,
    const float* __restrict__ bias, bf16* __restrict__ Cp)
{
    __shared__ __align__(16) bf16 lA[2][256 * 64];
    __shared__ __align__(16) bf16 lB[2][256 * 64];

    const int tid  = threadIdx.x;
    const int lane = tid & 63, wv = tid >> 6;
    const int wm = wv >> 2, wn = wv & 3;
    const int quad = lane >> 4, l16 = lane & 15;

    const int lid = blockIdx.y * 128 + blockIdx.x;
    const int wid = (lid & 7) * 64 + (lid >> 3);
    const int m0 = (wid >> 2) * 256;
    const int n0 = (wid & 3) * 256;

    const int sr = lane >> 3;
    const int sc = ((lane & 7) ^ sr) * 8;
    const int ar = tid >> 1;
    const int ah = tid & 1;

    f32x4 acc[8][4] = {};
    float4 vr[4][2];

#define STAGE_B6(buf, ko) do { \
    _Pragma("unroll") \
    for (int qi = 0; qi < 4; ++qi) { \
        const int q = wv * 4 + qi; \
        GLL16(Bt + (size_t)(n0 + q * 8 + sr) * 1024 + (ko) + sc, (char*)lB[buf] + q * 1024); \
    } } while (0)
#define LOAD_A_F326(ko) do { \
    _Pragma("unroll") \
    for (int i = 0; i < 4; ++i) { \
        const int c = ah * 4 + i; \
        const float* srcp = Af + (size_t)(m0 + ar) * 1024 + (ko) + c * 8; \
        vr[i][0] = *(const float4*)(srcp); \
        vr[i][1] = *(const float4*)(srcp + 4); \
    } } while (0)
#define WRITE_A_F326(buf) do { \
    _Pragma("unroll") \
    for (int i = 0; i < 4; ++i) { \
        const int c = ah * 4 + i; \
        s16x8 w; \
        w[0] = f2bf(vr[i][0].x); w[1] = f2bf(vr[i][0].y); w[2] = f2bf(vr[i][0].z); w[3] = f2bf(vr[i][0].w); \
        w[4] = f2bf(vr[i][1].x); w[5] = f2bf(vr[i][1].y); w[6] = f2bf(vr[i][1].z); w[7] = f2bf(vr[i][1].w); \
        *(s16x8*)((char*)lA[buf] + ar * 128 + ((c ^ (ar & 7)) << 4)) = w; \
    } } while (0)

    LOAD_A_F326(0); WRITE_A_F326(0);
    STAGE_B6(0, 0);
    __syncthreads();

    int cur = 0;
    for (int t = 0; t < 16; ++t) {
        const int nxt = cur ^ 1;
        if (t < 15) {
            LOAD_A_F326((t + 1) * 64);
            STAGE_B6(nxt, (t + 1) * 64);
        }
#pragma unroll
        for (int kc = 0; kc < 2; ++kc) {
            s16x8 af[8], bgv[4];
#pragma unroll
            for (int mt = 0; mt < 8; ++mt) {
                const int r = 128 * wm + 16 * mt + l16;
                const int c = kc * 4 + quad;
                af[mt] = *(const s16x8*)((const char*)lA[cur] + r * 128 + ((c ^ (r & 7)) * 16));
            }
#pragma unroll
            for (int nt = 0; nt < 4; ++nt) {
                const int r = 64 * wn + 16 * nt + l16;
                const int c = kc * 4 + quad;
                bgv[nt] = *(const s16x8*)((const char*)lB[cur] + r * 128 + ((c ^ (r & 7)) * 16));
            }
#pragma unroll
            for (int mt = 0; mt < 8; ++mt)
#pragma unroll
                for (int nt = 0; nt < 4; ++nt)
                    acc[mt][nt] = MFMA16(af[mt], bgv[nt], acc[mt][nt]);
        }
        if (t < 15) WRITE_A_F326(nxt);
        __syncthreads();
        cur = nxt;
    }
#undef STAGE_B6
#undef LOAD_A_F326
#undef WRITE_A_F326

    float bv[4];
#pragma unroll
    for (int nt = 0; nt < 4; ++nt)
        bv[nt] = bias[n0 + 64 * wn + 16 * nt + l16];

#pragma unroll
    for (int mt = 0; mt < 8; ++mt) {
#pragma unroll
        for (int r = 0; r < 4; ++r) {
            const int m = m0 + 128 * wm + 16 * mt + 4 * quad + r;
            const int om = ((m & 511) << 6) | (m >> 9);   // b*512+t -> t*64+b
#pragma unroll
            for (int nt = 0; nt < 4; ++nt) {
                const int n = n0 + 64 * wn + 16 * nt + l16;
                Cp[(size_t)om * 1024 + n] = __float2bfloat16(acc[mt][nt][r] + bv[nt]);
            }
        }
    }
}

// ---------------------------------------------------------------------------
// Power chain: D[z] = A[z] @ Bt^T.  dbuf-prefetch 128^2.  grid (8,8,z).
// ---------------------------------------------------------------------------
__global__ __launch_bounds__(256) void powmul(
    const bf16* __restrict__ Abase, const bf16* __restrict__ Bt,
    bf16* __restrict__ Dbase)
{
    __shared__ __align__(16) bf16 lA[2][128 * 64];
    __shared__ __align__(16) bf16 lB[2][128 * 64];
    const int tid  = threadIdx.x;
    const int lane = tid & 63, wv = tid >> 6;
    const int wm = wv & 1, wn = wv >> 1;
    const int quad = lane >> 4, l16 = lane & 15;
    const int m0 = blockIdx.x * 128, n0 = blockIdx.y * 128;
    const bf16* A = Abase + (size_t)blockIdx.z * 1048576;
    bf16* D       = Dbase + (size_t)blockIdx.z * 1048576;
    const int sr = lane >> 3;
    const int sc = ((lane & 7) ^ sr) * 8;

#define STAGE_AB(buf, ko) do { \
    _Pragma("unroll") \
    for (int qi = 0; qi < 4; ++qi) { \
        const int q = wv * 4 + qi; \
        GLL16(A  + (size_t)(m0 + q * 8 + sr) * 1024 + (ko) + sc, (char*)lA[buf] + q * 1024); \
        GLL16(Bt + (size_t)(n0 + q * 8 + sr) * 1024 + (ko) + sc, (char*)lB[buf] + q * 1024); \
    } } while (0)

    f32x4 acc[4][4] = {};
    STAGE_AB(0, 0);
    __syncthreads();
    int cur = 0;
    for (int t = 0; t < 16; ++t) {
        const int nxt = cur ^ 1;
        if (t < 15) STAGE_AB(nxt, (t + 1) * 64);
#pragma unroll
        for (int kc = 0; kc < 2; ++kc) {
            s16x8 af[4], bg[4];
#pragma unroll
            for (int mt = 0; mt < 4; ++mt) {
                const int r = 64 * wm + 16 * mt + l16;
                const int c = kc * 4 + quad;
                af[mt] = *(const s16x8*)((const char*)lA[cur] + r * 128 + ((c ^ (r & 7)) * 16));
            }
#pragma unroll
            for (int nt = 0; nt < 4; ++nt) {
                const int r = 64 * wn + 16 * nt + l16;
                const int c = kc * 4 + quad;
                bg[nt] = *(const s16x8*)((const char*)lB[cur] + r * 128 + ((c ^ (r & 7)) * 16));
            }
#pragma unroll
            for (int mt = 0; mt < 4; ++mt)
#pragma unroll
                for (int nt = 0; nt < 4; ++nt)
                    acc[mt][nt] = MFMA16(af[mt], bg[nt], acc[mt][nt]);
        }
        __syncthreads();
        cur = nxt;
    }
#undef STAGE_AB
#pragma unroll
    for (int mt = 0; mt < 4; ++mt)
#pragma unroll
        for (int r = 0; r < 4; ++r) {
            const int m = m0 + 64 * wm + 16 * mt + 4 * quad + r;
#pragma unroll
            for (int nt = 0; nt < 4; ++nt) {
                const int n = n0 + 64 * wn + 16 * nt + l16;
                D[(size_t)m * 1024 + n] = __float2bfloat16(acc[mt][nt][r]);
            }
        }
}

// ---------------------------------------------------------------------------
// Local scan step j: rows t = c*16+j:  UA[t] += UA[t-1] @ Waa^T
// dbuf-prefetch; 64x128 tile, 4 waves 64x32.  grid (32, 8).
// ---------------------------------------------------------------------------
__global__ __launch_bounds__(256) void local_step(
    const bf16* __restrict__ Bt, bf16* __restrict__ UA, int j)
{
    __shared__ __align__(16) bf16 lA[2][64 * 64];
    __shared__ __align__(16) bf16 lB[2][128 * 64];
    const int tid = threadIdx.x;
    const int lane = tid & 63, wv = tid >> 6;
    const int quad = lane >> 4, l16 = lane & 15;
    const int n0 = blockIdx.y * 128;
    const int t_ = blockIdx.x * 16 + j;
    const bf16* src = UA + (size_t)(t_ - 1) * 64 * 1024;
    bf16* dst       = UA + (size_t)t_ * 64 * 1024;
    const int sr = lane >> 3;
    const int sc = ((lane & 7) ^ sr) * 8;

#define STAGE_AB(buf, ko) do { \
    _Pragma("unroll") \
    for (int qi = 0; qi < 2; ++qi) { \
        const int q = wv * 2 + qi; \
        GLL16(src + (size_t)(q * 8 + sr) * 1024 + (ko) + sc, (char*)lA[buf] + q * 1024); \
    } \
    _Pragma("unroll") \
    for (int qi = 0; qi < 4; ++qi) { \
        const int q = wv * 4 + qi; \
        GLL16(Bt + (size_t)(n0 + q * 8 + sr) * 1024 + (ko) + sc, (char*)lB[buf] + q * 1024); \
    } } while (0)

    f32x4 acc[4][2] = {};
    STAGE_AB(0, 0);
    __syncthreads();
    int cur = 0;
    for (int t = 0; t < 16; ++t) {
        const int nxt = cur ^ 1;
        if (t < 15) STAGE_AB(nxt, (t + 1) * 64);
#pragma unroll
        for (int kc = 0; kc < 2; ++kc) {
            s16x8 af[4], bg[2];
#pragma unroll
            for (int mt = 0; mt < 4; ++mt) {
                const int r = 16 * mt + l16;
                const int c = kc * 4 + quad;
                af[mt] = *(const s16x8*)((const char*)lA[cur] + r * 128 + ((c ^ (r & 7)) * 16));
            }
#pragma unroll
            for (int nt = 0; nt < 2; ++nt) {
                const int r = 32 * wv + 16 * nt + l16;
                const int c = kc * 4 + quad;
                bg[nt] = *(const s16x8*)((const char*)lB[cur] + r * 128 + ((c ^ (r & 7)) * 16));
            }
#pragma unroll
            for (int mt = 0; mt < 4; ++mt)
#pragma unroll
                for (int nt = 0; nt < 2; ++nt)
                    acc[mt][nt] = MFMA16(af[mt], bg[nt], acc[mt][nt]);
        }
        __syncthreads();
        cur = nxt;
    }
#undef STAGE_AB
#pragma unroll
    for (int mt = 0; mt < 4; ++mt)
#pragma unroll
        for (int r = 0; r < 4; ++r) {
            const int b = 16 * mt + 4 * quad + r;
#pragma unroll
            for (int nt = 0; nt < 2; ++nt) {
                const int n = n0 + 32 * wv + 16 * nt + l16;
                bf16* p = dst + (size_t)b * 1024 + n;
                *p = __float2bfloat16(acc[mt][nt][r] + __bfloat162float(*p));
            }
        }
}

// ---------------------------------------------------------------------------
// Carry step: dst[b][n] = lend[b][n] + sum_k src[b][k] * P16[n][k]
// Launch-latency floor; unchanged.  256 blocks x 1 wave.
// ---------------------------------------------------------------------------
__global__ __launch_bounds__(64, 1) void carry_step(
    const bf16* __restrict__ P16, const bf16* __restrict__ lend,
    const bf16* __restrict__ src, bf16* __restrict__ dst)
{
    const int lane = threadIdx.x;
    const int quad = lane >> 4, l16 = lane & 15;
    const int bi = blockIdx.x & 3, nj = blockIdx.x >> 2;

    const bf16* arow = src + ((size_t)(16 * bi + l16)) * 1024;
    const bf16* wrow = P16 + ((size_t)(16 * nj + l16)) * 1024;

    const bf16* urow = lend + ((size_t)(16 * bi + 4 * quad)) * 1024 + 16 * nj + l16;
    f32x4 acc;
#pragma unroll
    for (int rr = 0; rr < 4; ++rr)
        acc[rr] = __bfloat162float(urow[(size_t)rr * 1024]);

    s16x8 av[32], wf[32];
#pragma unroll
    for (int kc = 0; kc < 32; ++kc) {
        av[kc] = *(const s16x8*)(arow + kc * 32 + quad * 8);
        wf[kc] = *(const s16x8*)(wrow + kc * 32 + quad * 8);
    }
#pragma unroll
    for (int kc = 0; kc < 32; ++kc)
        acc = MFMA16(av[kc], wf[kc], acc);

    bf16* drow = dst + ((size_t)(16 * bi + 4 * quad)) * 1024 + 16 * nj + l16;
#pragma unroll
    for (int rr = 0; rr < 4; ++rr)
        drow[(size_t)rr * 1024] = __float2bfloat16(acc[rr]);
}

// ---------------------------------------------------------------------------
// Blocked linear scan, S=16 chunk, G=32 chunks (see round-1 derivation).
// ---------------------------------------------------------------------------
extern "C" void kernel_launch(void* const* d_in, const int* in_sizes, int n_in,
                              void* d_out, int out_size, void* d_ws, size_t ws_size,
                              hipStream_t stream) {
    const float* X   = (const float*)d_in[0];   // [64,512,1024] f32
    const float* Wax = (const float*)d_in[1];   // [1024,1024]   f32
    const float* Waa = (const float*)d_in[2];   // [1024,1024]   f32
    const float* ba  = (const float*)d_in[3];   // [1024]        f32
    const float* Wy  = (const float*)d_in[4];   // [1024,1024]   f32
    const float* by  = (const float*)d_in[5];   // [1024]        f32

    char* ws = (char*)d_ws;
    bf16* UA   = (bf16*)ws;                       // 64 MB: [512][64][1024]
    bf16* PB   = (bf16*)(ws + 67108864);          // 32 MB: PB[k] = W^{k+1}, k=0..15
    bf16* Waxb = (bf16*)(ws + 100663296);         // 2 MB
    bf16* Wyb  = (bf16*)(ws + 102760448);         // 2 MB
    bf16* CIN  = (bf16*)(ws + 104857600);         // 4 MB: [32][64][1024] carry-in per chunk
    bf16* Tb   = CIN;                             // 2 MB transpose scratch (dead before carries)
    const size_t MM = 1048576;                    // elems per 1024x1024 matrix

    const int NW = 1024 * 1024;
    cvt_bf16<<<dim3(NW / 1024), dim3(256), 0, stream>>>(Wax, Waxb, NW);
    cvt_bf16<<<dim3(NW / 1024), dim3(256), 0, stream>>>(Waa, PB,   NW);   // PB[0] = W
    cvt_bf16<<<dim3(NW / 1024), dim3(256), 0, stream>>>(Wy,  Wyb,  NW);

    dim3 gridG(128, 4), blk2(512), blk(256);
    // Phase A: U = X @ Wax^T + ba   (f32 A, rows b*512+t -> t*64+b, bf16 out)
    gemm_bt256_af32<<<gridG, blk2, 0, stream>>>(X, Waxb, ba, UA);

    // Powers of W (log-depth; powers commute so only P_{2^k}^T is ever needed):
    transpose_bf16<<<dim3(16, 16), blk, 0, stream>>>(PB, Tb);              // W^T
    powmul<<<dim3(8, 8, 1), blk, 0, stream>>>(PB, Tb, PB + 1 * MM);        // P2 = W*W
    transpose_bf16<<<dim3(16, 16), blk, 0, stream>>>(PB + 1 * MM, Tb);     // P2^T
    powmul<<<dim3(8, 8, 2), blk, 0, stream>>>(PB, Tb, PB + 2 * MM);        // P3,P4 = {P1,P2}*P2
    transpose_bf16<<<dim3(16, 16), blk, 0, stream>>>(PB + 3 * MM, Tb);     // P4^T
    powmul<<<dim3(8, 8, 4), blk, 0, stream>>>(PB, Tb, PB + 4 * MM);        // P5..P8 = {P1..P4}*P4
    transpose_bf16<<<dim3(16, 16), blk, 0, stream>>>(PB + 7 * MM, Tb);     // P8^T
    powmul<<<dim3(8, 8, 8), blk, 0, stream>>>(PB, Tb, PB + 8 * MM);        // P9..P16 = {P1..P8}*P8

    // Local chunk scans: depth 15, all 32 chunks in parallel per launch.
    for (int j = 1; j < 16; ++j)
        local_step<<<dim3(32, 8), blk, 0, stream>>>(PB, UA, j);

    // Carry scan over chunk ends: CIN[c] = A_end[c-1]; CIN[0] = 0.
    zero_bf16<<<dim3(32), dim3(256), 0, stream>>>(CIN, 65536);
    for (int c = 1; c < 32; ++c)
        carry_step<<<dim3(256), dim3(64), 0, stream>>>(
            PB + 15 * MM,
            UA  + (size_t)((c - 1) * 16 + 15) * 65536,
            CIN + (size_t)(c - 1) * 65536,
            CIN + (size_t)c * 65536);

    // Fix-up: UA[c*16+j] += CIN[c] @ (W^{j+1})^T, one parallel launch (8-phase).
    fixup8<<<dim3(8, 4, 16), blk2, 0, stream>>>(CIN, PB, UA);

    // Phase C: Y = A @ Wy^T + by    (rows t*64+b -> b*512+t, f32 out, 8-phase)
    gemm8<true, 2><<<gridG, blk2, 0, stream>>>(UA, Wyb, by, (float*)d_out);
}